// Round 1
// baseline (2124.426 us; speedup 1.0000x reference)
//
#include <hip/hip_runtime.h>
#include <math.h>

#define G_NUM 1024
#define H 128
#define NNODES 100000
#define NEDGES 500000
#define EPS_LN 1e-5f
#define TILE 16

__device__ __forceinline__ float gelu_exact(float x) {
    return 0.5f * x * (1.0f + erff(x * 0.70710678118654752440f));
}
// order-preserving float<->uint encoding for atomic max
__device__ __forceinline__ unsigned fenc(float f) {
    unsigned b = __float_as_uint(f);
    return (b & 0x80000000u) ? ~b : (b | 0x80000000u);
}
__device__ __forceinline__ float fdec(unsigned k) {
    return __uint_as_float((k & 0x80000000u) ? (k & 0x7FFFFFFFu) : ~k);
}

// ---- K0: probe selected_mask storage dtype ----------------------------------
// byte-bool words have bytes in {0,1}; int32 words are {0,1}; f32 words are
// {0, 0x3F800000}. Distinguishable from the first 256 words (1 KB, safe for
// the smallest candidate buffer of 500 KB).
__global__ void k_probe_mask(const unsigned* __restrict__ mw, int* __restrict__ flag) {
    unsigned v = mw[threadIdx.x];
    if (v == 0x3F800000u) atomicOr(flag, 2);
    else if (v > 1u) atomicOr(flag, 1);
}

// ---- K1: aggregate_start -> summary[G,H] ------------------------------------
__global__ __launch_bounds__(128) void k_start(
    const float* __restrict__ node_tokens, const float* __restrict__ question,
    const int* __restrict__ locals_, const int* __restrict__ ptr,
    float* __restrict__ summary)
{
    int g = blockIdx.x, t = threadIdx.x;
    __shared__ float red[2];
    __shared__ float sc[16];
    int p0 = ptr[g], p1 = ptr[g + 1];
    int cnt = p1 - p0; if (cnt > 16) cnt = 16;
    float q = question[(size_t)g * H + t];
    for (int s = 0; s < cnt; ++s) {
        int node = locals_[p0 + s];
        float v = node_tokens[(size_t)node * H + t] * q;
        for (int off = 32; off; off >>= 1) v += __shfl_down(v, off);
        if ((t & 63) == 0) red[t >> 6] = v;
        __syncthreads();
        if (t == 0) sc[s] = (red[0] + red[1]) * 0.08838834764831845f; // 1/sqrt(128)
        __syncthreads();
    }
    // softmax over sc[0..cnt) (redundant per-thread, cheap)
    float m = -1e30f;
    for (int s = 0; s < cnt; ++s) m = fmaxf(m, sc[s]);
    float den = 0.f;
    for (int s = 0; s < cnt; ++s) den += expf(sc[s] - m);
    float acc = 0.f;
    for (int s = 0; s < cnt; ++s) {
        float a = expf(sc[s] - m) / den;
        acc += a * node_tokens[(size_t)locals_[p0 + s] * H + t];
    }
    summary[(size_t)g * H + t] = acc;
}

// ---- K2: context MLP + log_z head -> out[:,0] -------------------------------
__global__ __launch_bounds__(128) void k_graph(
    const float* __restrict__ summary, const float* __restrict__ question,
    const float* __restrict__ cw1, const float* __restrict__ cb1,
    const float* __restrict__ cw2, const float* __restrict__ cb2,
    const float* __restrict__ ln1g, const float* __restrict__ ln1b,
    const float* __restrict__ zw1, const float* __restrict__ zb1,
    const float* __restrict__ zw2, const float* __restrict__ zb2,
    float* __restrict__ out)
{
    int g = blockIdx.x, t = threadIdx.x;
    __shared__ float xin[2 * H];
    __shared__ float buf[H];
    __shared__ float r1[2], r2[2];
    xin[t]     = summary[(size_t)g * H + t];
    xin[H + t] = question[(size_t)g * H + t];
    __syncthreads();
    float a1 = cb1[t];
    for (int k = 0; k < 2 * H; ++k) a1 += xin[k] * cw1[k * H + t];
    buf[t] = gelu_exact(a1);
    __syncthreads();
    float ctx = cb2[t];
    for (int k = 0; k < H; ++k) ctx += buf[k] * cw2[k * H + t];
    // LayerNorm over the 128 ctx values held one-per-thread
    float s1 = ctx, s2 = ctx * ctx;
    for (int off = 32; off; off >>= 1) { s1 += __shfl_down(s1, off); s2 += __shfl_down(s2, off); }
    if ((t & 63) == 0) { r1[t >> 6] = s1; r2[t >> 6] = s2; }
    __syncthreads();
    float mean = (r1[0] + r1[1]) * (1.f / H);
    float var  = (r2[0] + r2[1]) * (1.f / H) - mean * mean;
    float xn = (ctx - mean) * rsqrtf(var + EPS_LN) * ln1g[t] + ln1b[t];
    __syncthreads();
    buf[t] = xn;
    __syncthreads();
    float a2 = zb1[t];
    for (int k = 0; k < H; ++k) a2 += buf[k] * zw1[k * H + t];
    float p = gelu_exact(a2) * zw2[t];
    for (int off = 32; off; off >>= 1) p += __shfl_down(p, off);
    if ((t & 63) == 0) r1[t >> 6] = p;
    __syncthreads();
    if (t == 0) out[(size_t)g * 3 + 0] = r1[0] + r1[1] + zb2[0];
}

// ---- K4: edge MLP -> logits[E], atomic segment-max over tgt -----------------
__global__ __launch_bounds__(256) void k_edges(
    const float* __restrict__ node_tokens, const float* __restrict__ question,
    const float* __restrict__ edge_tokens, const int* __restrict__ edge_batch,
    const int* __restrict__ edge_index, const float* __restrict__ blng,
    const float* __restrict__ blnb, const float* __restrict__ bw1,
    const float* __restrict__ bb1, const float* __restrict__ bw2,
    const float* __restrict__ bb2, float* __restrict__ logits,
    unsigned* __restrict__ tmaxk)
{
    __shared__ float xs[TILE][3 * H];   // 24 KB
    __shared__ float lred[4][TILE];
    int t = threadIdx.x;
    int e0 = blockIdx.x * TILE;         // E = 31250 * 16 exactly

    // stage concat(edge_tok, question[edge_batch], node_tok[tgt]) into LDS
    for (int idx = t; idx < TILE * 96; idx += 256) {
        int i = idx / 96, c = idx % 96;
        int e = e0 + i;
        const float4* src;
        if (c < 32)      src = (const float4*)(edge_tokens + (size_t)e * H) + c;
        else if (c < 64) src = (const float4*)(question + (size_t)edge_batch[e] * H) + (c - 32);
        else             src = (const float4*)(node_tokens + (size_t)edge_index[NEDGES + e] * H) + (c - 64);
        ((float4*)&xs[i][0])[c] = *src;
    }
    __syncthreads();

    // LayerNorm(384) — one wave per edge, 4 edges per wave
    int lane = t & 63, w = t >> 6;
    for (int i = w; i < TILE; i += 4) {
        float s1 = 0.f, s2 = 0.f;
        for (int k = lane; k < 384; k += 64) { float x = xs[i][k]; s1 += x; s2 += x * x; }
        for (int off = 32; off; off >>= 1) { s1 += __shfl_down(s1, off); s2 += __shfl_down(s2, off); }
        s1 = __shfl(s1, 0); s2 = __shfl(s2, 0);
        float mean = s1 * (1.f / 384.f);
        float var  = s2 * (1.f / 384.f) - mean * mean;
        float inv  = rsqrtf(var + EPS_LN);
        for (int k = lane; k < 384; k += 64)
            xs[i][k] = (xs[i][k] - mean) * inv * blng[k] + blnb[k];
    }
    __syncthreads();

    // [16,384] @ [384,128]: thread (half=t>>7, j=t&127) computes 8 edges
    int j = t & 127;
    int ibase = (t >> 7) * 8;
    float acc[8];
    float b1 = bb1[j];
    #pragma unroll
    for (int r = 0; r < 8; ++r) acc[r] = b1;
    for (int k = 0; k < 384; ++k) {
        float wv = bw1[k * H + j];
        #pragma unroll
        for (int r = 0; r < 8; ++r) acc[r] += xs[ibase + r][k] * wv;
    }
    // second layer: gelu then dot with bw2 across j
    float w2 = bw2[j];
    float p[8];
    #pragma unroll
    for (int r = 0; r < 8; ++r) p[r] = gelu_exact(acc[r]) * w2;
    #pragma unroll
    for (int r = 0; r < 8; ++r)
        for (int off = 32; off; off >>= 1) p[r] += __shfl_down(p[r], off);
    if (lane == 0) {
        #pragma unroll
        for (int r = 0; r < 8; ++r) lred[w][ibase + r - ((w >> 1) ? 8 : 0) + ((w >> 1) ? 8 : 0)] = 0.f; // placeholder no-op avoided below
    }
    if (lane == 0) {
        #pragma unroll
        for (int r = 0; r < 8; ++r) lred[w][r] = p[r];
    }
    __syncthreads();
    if (t < TILE) {
        int i = t;
        int wpair = (i >> 3) * 2;
        float lg = lred[wpair][i & 7] + lred[wpair + 1][i & 7] + bb2[0];
        int e = e0 + i;
        logits[e] = lg;
        atomicMax(&tmaxk[edge_index[NEDGES + e]], fenc(lg));
    }
}

// ---- K5: segment sum of exp(logit - max) over tgt ---------------------------
__global__ void k_sumexp(const float* __restrict__ logits,
                         const int* __restrict__ edge_index,
                         const unsigned* __restrict__ tmaxk,
                         float* __restrict__ sumexp)
{
    int e = blockIdx.x * blockDim.x + threadIdx.x;
    if (e >= NEDGES) return;
    int tg = edge_index[NEDGES + e];
    atomicAdd(&sumexp[tg], expf(logits[e] - fdec(tmaxk[tg])));
}

// ---- K6: masked per-graph sum of log-probs ----------------------------------
__global__ void k_logpb(const float* __restrict__ logits,
                        const int* __restrict__ edge_index,
                        const int* __restrict__ edge_batch,
                        const void* __restrict__ mask,
                        const int* __restrict__ flag,
                        const unsigned* __restrict__ tmaxk,
                        const float* __restrict__ sumexp,
                        float* __restrict__ logpb, int* __restrict__ selcnt)
{
    int e = blockIdx.x * blockDim.x + threadIdx.x;
    if (e >= NEDGES) return;
    int mode = *flag;
    bool sel;
    if (mode & 2)      sel = ((const float*)mask)[e] != 0.f;
    else if (mode & 1) sel = ((const unsigned char*)mask)[e] != 0;
    else               sel = ((const int*)mask)[e] != 0;
    if (!sel) return;
    int tg = edge_index[NEDGES + e];
    float lp = logits[e] - fdec(tmaxk[tg]) - logf(sumexp[tg]);
    int g = edge_batch[e];
    atomicAdd(&logpb[g], lp);
    atomicAdd(&selcnt[g], 1);
}

// ---- K7: finalize out[:,1] and out[:,2] -------------------------------------
__global__ __launch_bounds__(1024) void k_final(const float* __restrict__ logpb,
                                                const int* __restrict__ selcnt,
                                                float* __restrict__ out)
{
    int g = threadIdx.x;
    float lpb = logpb[g];
    int has = selcnt[g] > 0;
    float s = has ? -lpb : 0.f;
    int c = has;
    __shared__ float rn[16];
    __shared__ int rh[16];
    __shared__ float pbnll_s;
    for (int off = 32; off; off >>= 1) { s += __shfl_down(s, off); c += __shfl_down(c, off); }
    if ((g & 63) == 0) { rn[g >> 6] = s; rh[g >> 6] = c; }
    __syncthreads();
    if (g == 0) {
        float ts = 0.f; int tc = 0;
        for (int i = 0; i < 16; ++i) { ts += rn[i]; tc += rh[i]; }
        pbnll_s = ts / (float)(tc > 0 ? tc : 1);
    }
    __syncthreads();
    out[(size_t)g * 3 + 1] = lpb;
    out[(size_t)g * 3 + 2] = pbnll_s;
}

extern "C" void kernel_launch(void* const* d_in, const int* in_sizes, int n_in,
                              void* d_out, int out_size, void* d_ws, size_t ws_size,
                              hipStream_t stream) {
    const float* node_tokens = (const float*)d_in[0];
    const float* question    = (const float*)d_in[1];
    const float* edge_tokens = (const float*)d_in[2];
    const int*   locals_     = (const int*)d_in[3];
    const int*   ptr         = (const int*)d_in[4];
    const int*   edge_batch  = (const int*)d_in[5];
    const void*  mask        = d_in[6];
    const int*   edge_index  = (const int*)d_in[7];
    const float* ln1g = (const float*)d_in[8];
    const float* ln1b = (const float*)d_in[9];
    const float* zw1  = (const float*)d_in[10];
    const float* zb1  = (const float*)d_in[11];
    const float* zw2  = (const float*)d_in[12];
    const float* zb2  = (const float*)d_in[13];
    const float* cw1  = (const float*)d_in[14];
    const float* cb1  = (const float*)d_in[15];
    const float* cw2  = (const float*)d_in[16];
    const float* cb2  = (const float*)d_in[17];
    const float* blng = (const float*)d_in[18];
    const float* blnb = (const float*)d_in[19];
    const float* bw1  = (const float*)d_in[20];
    const float* bb1  = (const float*)d_in[21];
    const float* bw2  = (const float*)d_in[22];
    const float* bb2  = (const float*)d_in[23];
    float* out = (float*)d_out;

    // workspace layout (floats)
    float* ws = (float*)d_ws;
    float*    summary = ws;                            // 131072
    float*    logits  = ws + 131072;                   // 500000
    unsigned* tmaxk   = (unsigned*)(ws + 631072);      // 100000 (0 == encoded < any real)
    float*    sumexp  = ws + 731072;                   // 100000
    float*    logpb   = ws + 831072;                   // 1024
    int*      selcnt  = (int*)(ws + 832096);           // 1024
    int*      flag    = (int*)(ws + 833120);           // 1
    size_t total_bytes = (size_t)833121 * 4;

    hipMemsetAsync(d_ws, 0, total_bytes, stream);
    k_probe_mask<<<1, 256, 0, stream>>>((const unsigned*)mask, flag);
    k_start<<<G_NUM, 128, 0, stream>>>(node_tokens, question, locals_, ptr, summary);
    k_graph<<<G_NUM, 128, 0, stream>>>(summary, question, cw1, cb1, cw2, cb2,
                                       ln1g, ln1b, zw1, zb1, zw2, zb2, out);
    k_edges<<<NEDGES / TILE, 256, 0, stream>>>(node_tokens, question, edge_tokens,
                                               edge_batch, edge_index, blng, blnb,
                                               bw1, bb1, bw2, bb2, logits, tmaxk);
    int eb = (NEDGES + 255) / 256;
    k_sumexp<<<eb, 256, 0, stream>>>(logits, edge_index, tmaxk, sumexp);
    k_logpb<<<eb, 256, 0, stream>>>(logits, edge_index, edge_batch, mask, flag,
                                    tmaxk, sumexp, logpb, selcnt);
    k_final<<<1, 1024, 0, stream>>>(logpb, selcnt, out);
}

// Round 2
// 689.663 us; speedup vs baseline: 3.0804x; 3.0804x over previous
//
#include <hip/hip_runtime.h>
#include <math.h>

#define G_NUM 1024
#define H 128
#define NNODES 100000
#define NEDGES 500000
#define EPS_LN 1e-5f

typedef __attribute__((ext_vector_type(8))) short short8;
typedef __attribute__((ext_vector_type(4))) float f32x4;

__device__ __forceinline__ float gelu_exact(float x) {
    return 0.5f * x * (1.0f + erff(x * 0.70710678118654752440f));
}
__device__ __forceinline__ unsigned fenc(float f) {
    unsigned b = __float_as_uint(f);
    return (b & 0x80000000u) ? ~b : (b | 0x80000000u);
}
__device__ __forceinline__ float fdec(unsigned k) {
    return __uint_as_float((k & 0x80000000u) ? (k & 0x7FFFFFFFu) : ~k);
}
__device__ __forceinline__ unsigned short f2bf(float x) {
    unsigned u = __float_as_uint(x);
    return (unsigned short)((u + 0x7FFFu + ((u >> 16) & 1u)) >> 16);
}
__device__ __forceinline__ float bf2f(unsigned short h) {
    return __uint_as_float(((unsigned)h) << 16);
}

// ---- K0: probe selected_mask storage dtype ----------------------------------
__global__ void k_probe_mask(const unsigned* __restrict__ mw, int* __restrict__ flag) {
    unsigned v = mw[threadIdx.x];
    if (v == 0x3F800000u) atomicOr(flag, 2);
    else if (v > 1u) atomicOr(flag, 1);
}

// ---- K_prep: bw1 f32 [384][128] -> bf16 in B-fragment order -----------------
// dst index: ((s*8 + t)*64 + lane)*8 + j  with  s=k>>5, quad=(k&31)>>3,
// j=k&7, lane=quad*16+(n&15), t=n>>4
__global__ void k_prep(const float* __restrict__ bw1, unsigned short* __restrict__ bwbf) {
    int e = blockIdx.x * 256 + threadIdx.x;
    if (e >= 384 * 128) return;
    int k = e >> 7, n = e & 127;
    int s = k >> 5, krel = k & 31;
    int quad = krel >> 3, j = krel & 7;
    int lane = quad * 16 + (n & 15);
    int t = n >> 4;
    bwbf[((s * 8 + t) * 64 + lane) * 8 + j] = f2bf(bw1[e]);
}

// ---- K1: aggregate_start -> summary[G,H] ------------------------------------
__global__ __launch_bounds__(128) void k_start(
    const float* __restrict__ node_tokens, const float* __restrict__ question,
    const int* __restrict__ locals_, const int* __restrict__ ptr,
    float* __restrict__ summary)
{
    int g = blockIdx.x, t = threadIdx.x;
    __shared__ float red[2];
    __shared__ float sc[16];
    int p0 = ptr[g], p1 = ptr[g + 1];
    int cnt = p1 - p0; if (cnt > 16) cnt = 16;
    float q = question[(size_t)g * H + t];
    for (int s = 0; s < cnt; ++s) {
        int node = locals_[p0 + s];
        float v = node_tokens[(size_t)node * H + t] * q;
        for (int off = 32; off; off >>= 1) v += __shfl_down(v, off);
        if ((t & 63) == 0) red[t >> 6] = v;
        __syncthreads();
        if (t == 0) sc[s] = (red[0] + red[1]) * 0.08838834764831845f;
        __syncthreads();
    }
    float m = -1e30f;
    for (int s = 0; s < cnt; ++s) m = fmaxf(m, sc[s]);
    float den = 0.f;
    for (int s = 0; s < cnt; ++s) den += expf(sc[s] - m);
    float acc = 0.f;
    for (int s = 0; s < cnt; ++s) {
        float a = expf(sc[s] - m) / den;
        acc += a * node_tokens[(size_t)locals_[p0 + s] * H + t];
    }
    summary[(size_t)g * H + t] = acc;
}

// ---- K2: context MLP + log_z head -> out[:,0] -------------------------------
__global__ __launch_bounds__(128) void k_graph(
    const float* __restrict__ summary, const float* __restrict__ question,
    const float* __restrict__ cw1, const float* __restrict__ cb1,
    const float* __restrict__ cw2, const float* __restrict__ cb2,
    const float* __restrict__ ln1g, const float* __restrict__ ln1b,
    const float* __restrict__ zw1, const float* __restrict__ zb1,
    const float* __restrict__ zw2, const float* __restrict__ zb2,
    float* __restrict__ out)
{
    int g = blockIdx.x, t = threadIdx.x;
    __shared__ float xin[2 * H];
    __shared__ float buf[H];
    __shared__ float r1[2], r2[2];
    xin[t]     = summary[(size_t)g * H + t];
    xin[H + t] = question[(size_t)g * H + t];
    __syncthreads();
    float a1 = cb1[t];
    for (int k = 0; k < 2 * H; ++k) a1 += xin[k] * cw1[k * H + t];
    buf[t] = gelu_exact(a1);
    __syncthreads();
    float ctx = cb2[t];
    for (int k = 0; k < H; ++k) ctx += buf[k] * cw2[k * H + t];
    float s1 = ctx, s2 = ctx * ctx;
    for (int off = 32; off; off >>= 1) { s1 += __shfl_down(s1, off); s2 += __shfl_down(s2, off); }
    if ((t & 63) == 0) { r1[t >> 6] = s1; r2[t >> 6] = s2; }
    __syncthreads();
    float mean = (r1[0] + r1[1]) * (1.f / H);
    float var  = (r2[0] + r2[1]) * (1.f / H) - mean * mean;
    float xn = (ctx - mean) * rsqrtf(var + EPS_LN) * ln1g[t] + ln1b[t];
    __syncthreads();
    buf[t] = xn;
    __syncthreads();
    float a2 = zb1[t];
    for (int k = 0; k < H; ++k) a2 += buf[k] * zw1[k * H + t];
    float p = gelu_exact(a2) * zw2[t];
    for (int off = 32; off; off >>= 1) p += __shfl_down(p, off);
    if ((t & 63) == 0) r1[t >> 6] = p;
    __syncthreads();
    if (t == 0) out[(size_t)g * 3 + 0] = r1[0] + r1[1] + zb2[0];
}

// ---- K4: edge MLP via MFMA -> logits[E], atomic segment-max over tgt --------
// block = 64 edges, 4 waves; wave w computes edges [w*16, w*16+16), all 128 n
#define XPITCH 392   // bf16 elements per row (784 B: 16-B aligned, bank-safe)
__global__ __launch_bounds__(256) void k_edges(
    const float* __restrict__ node_tokens, const float* __restrict__ question,
    const float* __restrict__ edge_tokens, const int* __restrict__ edge_batch,
    const int* __restrict__ edge_index, const float* __restrict__ blng,
    const float* __restrict__ blnb, const unsigned short* __restrict__ bwbf,
    const float* __restrict__ bb1, const float* __restrict__ bw2,
    const float* __restrict__ bb2, float* __restrict__ logits,
    unsigned* __restrict__ tmaxk)
{
    __shared__ unsigned short xbf[64 * XPITCH];   // 50176 B
    __shared__ unsigned short bstage[4096];       // 8192 B
    __shared__ float red1[64][4];                 // 1024 B
    __shared__ float red2[64][4];                 // 1024 B
    __shared__ float minv[64][2];                 // 512 B

    int t = threadIdx.x;
    int e0 = blockIdx.x * 64;

    // ---- Phase A: gather (4 threads per edge), f32 stats, bf16 store --------
    int i = t >> 2, sub = t & 3;
    int e = e0 + i; int ec = e < NEDGES ? e : NEDGES - 1;
    int qrow = edge_batch[ec];
    int trow = edge_index[NEDGES + ec];
    float s1 = 0.f, s2 = 0.f;
    #pragma unroll
    for (int k = 0; k < 24; ++k) {
        int c = sub + 4 * k;                       // float4 chunk 0..95
        const float4* src;
        if (c < 32)      src = (const float4*)(edge_tokens + (size_t)ec * H) + c;
        else if (c < 64) src = (const float4*)(question + (size_t)qrow * H) + (c - 32);
        else             src = (const float4*)(node_tokens + (size_t)trow * H) + (c - 64);
        float4 v = *src;
        s1 += v.x + v.y + v.z + v.w;
        s2 += v.x * v.x + v.y * v.y + v.z * v.z + v.w * v.w;
        unsigned short* dst = &xbf[i * XPITCH + c * 4];
        dst[0] = f2bf(v.x); dst[1] = f2bf(v.y); dst[2] = f2bf(v.z); dst[3] = f2bf(v.w);
    }
    red1[i][sub] = s1; red2[i][sub] = s2;
    __syncthreads();
    if (t < 64) {
        float a = red1[t][0] + red1[t][1] + red1[t][2] + red1[t][3];
        float b = red2[t][0] + red2[t][1] + red2[t][2] + red2[t][3];
        float mean = a * (1.f / 384.f);
        float var  = b * (1.f / 384.f) - mean * mean;
        minv[t][0] = mean; minv[t][1] = rsqrtf(var + EPS_LN);
    }
    __syncthreads();
    // ---- Phase B: normalize in place ----------------------------------------
    {
        float mean = minv[i][0], inv = minv[i][1];
        #pragma unroll
        for (int k = 0; k < 24; ++k) {
            int c = sub + 4 * k;
            float4 gv = *((const float4*)(blng) + c);
            float4 bv = *((const float4*)(blnb) + c);
            unsigned short* p = &xbf[i * XPITCH + c * 4];
            p[0] = f2bf((bf2f(p[0]) - mean) * inv * gv.x + bv.x);
            p[1] = f2bf((bf2f(p[1]) - mean) * inv * gv.y + bv.y);
            p[2] = f2bf((bf2f(p[2]) - mean) * inv * gv.z + bv.z);
            p[3] = f2bf((bf2f(p[3]) - mean) * inv * gv.w + bv.w);
        }
    }

    // ---- Phase C: MFMA K-loop ----------------------------------------------
    int lane = t & 63, w = t >> 6;
    int n16 = lane & 15, quad = lane >> 4;
    f32x4 acc[8];
    #pragma unroll
    for (int q = 0; q < 8; ++q) acc[q] = (f32x4){0.f, 0.f, 0.f, 0.f};

    for (int s = 0; s < 12; ++s) {
        __syncthreads();   // protect bstage from previous readers (and phase B first time)
        // stage 8 KB B-chunk: straight copy, 2 x 16 B per thread
        {
            const uint4* src = (const uint4*)(bwbf + s * 4096);
            uint4* dst = (uint4*)bstage;
            dst[t] = src[t];
            dst[t + 256] = src[t + 256];
        }
        __syncthreads();
        // a_frag: A[m = w*16 + n16][k = s*32 + quad*8 + j]
        short8 a = *(const short8*)&xbf[(w * 16 + n16) * XPITCH + s * 32 + quad * 8];
        #pragma unroll
        for (int t8 = 0; t8 < 8; ++t8) {
            short8 b = *(const short8*)&bstage[(t8 * 64 + lane) * 8];
            acc[t8] = __builtin_amdgcn_mfma_f32_16x16x32_bf16(a, b, acc[t8], 0, 0, 0);
        }
    }

    // ---- Epilogue: +bb1, GELU, dot bw2, reduce over 16 cols ----------------
    float bb1v[8], bw2v[8];
    #pragma unroll
    for (int t8 = 0; t8 < 8; ++t8) {
        bb1v[t8] = bb1[t8 * 16 + n16];
        bw2v[t8] = bw2[t8 * 16 + n16];
    }
    float bb2v = bb2[0];
    #pragma unroll
    for (int r = 0; r < 4; ++r) {
        float s = 0.f;
        #pragma unroll
        for (int t8 = 0; t8 < 8; ++t8)
            s += gelu_exact(acc[t8][r] + bb1v[t8]) * bw2v[t8];
        s += __shfl_xor(s, 1);
        s += __shfl_xor(s, 2);
        s += __shfl_xor(s, 4);
        s += __shfl_xor(s, 8);
        if (n16 == 0) {
            int ei = e0 + w * 16 + quad * 4 + r;
            if (ei < NEDGES) {
                float lg = s + bb2v;
                logits[ei] = lg;
                atomicMax(&tmaxk[edge_index[NEDGES + ei]], fenc(lg));
            }
        }
    }
}

// ---- K5: segment sum of exp(logit - max) over tgt ---------------------------
__global__ void k_sumexp(const float* __restrict__ logits,
                         const int* __restrict__ edge_index,
                         const unsigned* __restrict__ tmaxk,
                         float* __restrict__ sumexp)
{
    int e = blockIdx.x * blockDim.x + threadIdx.x;
    if (e >= NEDGES) return;
    int tg = edge_index[NEDGES + e];
    atomicAdd(&sumexp[tg], expf(logits[e] - fdec(tmaxk[tg])));
}

// ---- K6: masked per-graph sum of log-probs (LDS slot aggregation) -----------
__global__ __launch_bounds__(256) void k_logpb(
    const float* __restrict__ logits,
    const int* __restrict__ edge_index,
    const int* __restrict__ edge_batch,
    const void* __restrict__ mask,
    const int* __restrict__ flag,
    const unsigned* __restrict__ tmaxk,
    const float* __restrict__ sumexp,
    float* __restrict__ logpb, int* __restrict__ selcnt)
{
    __shared__ float lacc[8];
    __shared__ int lcnt[8];
    __shared__ int g0s, big;
    int t = threadIdx.x;
    int e0 = blockIdx.x * 256;
    if (t == 0) {
        int ga = edge_batch[e0 < NEDGES ? e0 : NEDGES - 1];
        int el = e0 + 255; if (el >= NEDGES) el = NEDGES - 1;
        int gb = edge_batch[el];
        g0s = ga; big = (gb - ga > 7);
    }
    if (t < 8) { lacc[t] = 0.f; lcnt[t] = 0; }
    __syncthreads();
    int e = e0 + t;
    if (e < NEDGES) {
        int mode = *flag;
        bool sel;
        if (mode & 2)      sel = ((const float*)mask)[e] != 0.f;
        else if (mode & 1) sel = ((const unsigned char*)mask)[e] != 0;
        else               sel = ((const int*)mask)[e] != 0;
        if (sel) {
            int tg = edge_index[NEDGES + e];
            float lp = logits[e] - fdec(tmaxk[tg]) - logf(sumexp[tg]);
            int g = edge_batch[e];
            if (!big) {
                atomicAdd(&lacc[g - g0s], lp);
                atomicAdd(&lcnt[g - g0s], 1);
            } else {
                atomicAdd(&logpb[g], lp);
                atomicAdd(&selcnt[g], 1);
            }
        }
    }
    __syncthreads();
    if (t < 8 && !big && lcnt[t] > 0) {
        atomicAdd(&logpb[g0s + t], lacc[t]);
        atomicAdd(&selcnt[g0s + t], lcnt[t]);
    }
}

// ---- K7: finalize out[:,1] and out[:,2] -------------------------------------
__global__ __launch_bounds__(1024) void k_final(const float* __restrict__ logpb,
                                                const int* __restrict__ selcnt,
                                                float* __restrict__ out)
{
    int g = threadIdx.x;
    float lpb = logpb[g];
    int has = selcnt[g] > 0;
    float s = has ? -lpb : 0.f;
    int c = has;
    __shared__ float rn[16];
    __shared__ int rh[16];
    __shared__ float pbnll_s;
    for (int off = 32; off; off >>= 1) { s += __shfl_down(s, off); c += __shfl_down(c, off); }
    if ((g & 63) == 0) { rn[g >> 6] = s; rh[g >> 6] = c; }
    __syncthreads();
    if (g == 0) {
        float ts = 0.f; int tc = 0;
        for (int i = 0; i < 16; ++i) { ts += rn[i]; tc += rh[i]; }
        pbnll_s = ts / (float)(tc > 0 ? tc : 1);
    }
    __syncthreads();
    out[(size_t)g * 3 + 1] = lpb;
    out[(size_t)g * 3 + 2] = pbnll_s;
}

extern "C" void kernel_launch(void* const* d_in, const int* in_sizes, int n_in,
                              void* d_out, int out_size, void* d_ws, size_t ws_size,
                              hipStream_t stream) {
    const float* node_tokens = (const float*)d_in[0];
    const float* question    = (const float*)d_in[1];
    const float* edge_tokens = (const float*)d_in[2];
    const int*   locals_     = (const int*)d_in[3];
    const int*   ptr         = (const int*)d_in[4];
    const int*   edge_batch  = (const int*)d_in[5];
    const void*  mask        = d_in[6];
    const int*   edge_index  = (const int*)d_in[7];
    const float* ln1g = (const float*)d_in[8];
    const float* ln1b = (const float*)d_in[9];
    const float* zw1  = (const float*)d_in[10];
    const float* zb1  = (const float*)d_in[11];
    const float* zw2  = (const float*)d_in[12];
    const float* zb2  = (const float*)d_in[13];
    const float* cw1  = (const float*)d_in[14];
    const float* cb1  = (const float*)d_in[15];
    const float* cw2  = (const float*)d_in[16];
    const float* cb2  = (const float*)d_in[17];
    const float* blng = (const float*)d_in[18];
    const float* blnb = (const float*)d_in[19];
    const float* bw1  = (const float*)d_in[20];
    const float* bb1  = (const float*)d_in[21];
    const float* bw2  = (const float*)d_in[22];
    const float* bb2  = (const float*)d_in[23];
    float* out = (float*)d_out;

    // workspace layout (floats); zeroed region first
    float* ws = (float*)d_ws;
    unsigned* tmaxk   = (unsigned*)ws;                 // 100000
    float*    sumexp  = ws + 100000;                   // 100000
    float*    logpb   = ws + 200000;                   // 1024
    int*      selcnt  = (int*)(ws + 201024);           // 1024
    int*      flag    = (int*)(ws + 202048);           // 1
    float*    summary = ws + 202052;                   // 131072
    float*    logits  = ws + 333124;                   // 500000
    unsigned short* bwbf = (unsigned short*)(ws + 833124); // 49152 bf16

    hipMemsetAsync(d_ws, 0, (size_t)202049 * 4, stream);
    k_probe_mask<<<1, 256, 0, stream>>>((const unsigned*)mask, flag);
    k_prep<<<192, 256, 0, stream>>>(bw1, bwbf);
    k_start<<<G_NUM, 128, 0, stream>>>(node_tokens, question, locals_, ptr, summary);
    k_graph<<<G_NUM, 128, 0, stream>>>(summary, question, cw1, cb1, cw2, cb2,
                                       ln1g, ln1b, zw1, zb1, zw2, zb2, out);
    k_edges<<<(NEDGES + 63) / 64, 256, 0, stream>>>(node_tokens, question, edge_tokens,
                                                    edge_batch, edge_index, blng, blnb,
                                                    bwbf, bb1, bw2, bb2, logits, tmaxk);
    int eb = (NEDGES + 255) / 256;
    k_sumexp<<<eb, 256, 0, stream>>>(logits, edge_index, tmaxk, sumexp);
    k_logpb<<<eb, 256, 0, stream>>>(logits, edge_index, edge_batch, mask, flag,
                                    tmaxk, sumexp, logpb, selcnt);
    k_final<<<1, 1024, 0, stream>>>(logpb, selcnt, out);
}

// Round 3
// 620.583 us; speedup vs baseline: 3.4233x; 1.1113x over previous
//
#include <hip/hip_runtime.h>
#include <math.h>

#define G_NUM 1024
#define H 128
#define NNODES 100000
#define NEDGES 500000
#define EPS_LN 1e-5f

typedef __attribute__((ext_vector_type(8))) short short8;
typedef __attribute__((ext_vector_type(4))) float f32x4;

__device__ __forceinline__ float gelu_exact(float x) {
    return 0.5f * x * (1.0f + erff(x * 0.70710678118654752440f));
}
__device__ __forceinline__ unsigned short f2bf(float x) {
    unsigned u = __float_as_uint(x);
    return (unsigned short)((u + 0x7FFFu + ((u >> 16) & 1u)) >> 16);
}

// ---- K0: probe selected_mask storage dtype ----------------------------------
__global__ void k_probe_mask(const unsigned* __restrict__ mw, int* __restrict__ flag) {
    unsigned v = mw[threadIdx.x];
    if (v == 0x3F800000u) atomicOr(flag, 2);
    else if (v > 1u) atomicOr(flag, 1);
}

// ---- K_prep: W1' = diag(blng)*bw1, bf16, B-fragment order -------------------
// dst: ((s*8 + t8)*64 + lane)*8 + j ; s=k>>5, quad=(k&31)>>3, j=k&7,
// lane=quad*16+(n&15), t8=n>>4
__global__ void k_prep(const float* __restrict__ bw1, const float* __restrict__ blng,
                       unsigned short* __restrict__ bwbf) {
    int e = blockIdx.x * 256 + threadIdx.x;
    if (e >= 384 * 128) return;
    int k = e >> 7, n = e & 127;
    int s = k >> 5, krel = k & 31;
    int quad = krel >> 3, j = krel & 7;
    int lane = quad * 16 + (n & 15);
    int t8 = n >> 4;
    bwbf[((s * 8 + t8) * 64 + lane) * 8 + j] = f2bf(bw1[e] * blng[k]);
}

// ---- K_prep2: colsum[n] = sum_k blng[k]*bw1[k][n]; bb1p[n] = bb1[n]+sum_k blnb[k]*bw1[k][n]
__global__ __launch_bounds__(128) void k_prep2(const float* __restrict__ bw1,
                                               const float* __restrict__ blng,
                                               const float* __restrict__ blnb,
                                               const float* __restrict__ bb1,
                                               float* __restrict__ colsum,
                                               float* __restrict__ bb1p) {
    int n = threadIdx.x;
    float cs = 0.f, bs = 0.f;
    for (int k = 0; k < 384; ++k) {
        float w = bw1[k * H + n];
        cs += blng[k] * w;
        bs += blnb[k] * w;
    }
    colsum[n] = cs;
    bb1p[n] = bb1[n] + bs;
}

// ---- K1: fused aggregate_start + context MLP + log_z -> out[:,0] ------------
__global__ __launch_bounds__(128) void k_graph(
    const float* __restrict__ node_tokens, const float* __restrict__ question,
    const int* __restrict__ locals_, const int* __restrict__ ptr,
    const float* __restrict__ cw1, const float* __restrict__ cb1,
    const float* __restrict__ cw2, const float* __restrict__ cb2,
    const float* __restrict__ ln1g, const float* __restrict__ ln1b,
    const float* __restrict__ zw1, const float* __restrict__ zb1,
    const float* __restrict__ zw2, const float* __restrict__ zb2,
    float* __restrict__ out)
{
    int g = blockIdx.x, t = threadIdx.x;
    __shared__ float xin[2 * H];
    __shared__ float buf[H];
    __shared__ float r1[2], r2[2];
    __shared__ float sc[16];
    // --- aggregate_start ---
    int p0 = ptr[g], p1 = ptr[g + 1];
    int cnt = p1 - p0; if (cnt > 16) cnt = 16;
    float q = question[(size_t)g * H + t];
    xin[H + t] = q;
    for (int s = 0; s < cnt; ++s) {
        int node = locals_[p0 + s];
        float v = node_tokens[(size_t)node * H + t] * q;
        for (int off = 32; off; off >>= 1) v += __shfl_down(v, off);
        if ((t & 63) == 0) r1[t >> 6] = v;
        __syncthreads();
        if (t == 0) sc[s] = (r1[0] + r1[1]) * 0.08838834764831845f;
        __syncthreads();
    }
    float m = -1e30f;
    for (int s = 0; s < cnt; ++s) m = fmaxf(m, sc[s]);
    float den = 0.f;
    for (int s = 0; s < cnt; ++s) den += expf(sc[s] - m);
    float acc0 = 0.f;
    for (int s = 0; s < cnt; ++s) {
        float a = expf(sc[s] - m) / den;
        acc0 += a * node_tokens[(size_t)locals_[p0 + s] * H + t];
    }
    xin[t] = acc0;
    __syncthreads();
    // --- ctx MLP ---
    float a1 = cb1[t];
    for (int k = 0; k < 2 * H; ++k) a1 += xin[k] * cw1[k * H + t];
    buf[t] = gelu_exact(a1);
    __syncthreads();
    float ctx = cb2[t];
    for (int k = 0; k < H; ++k) ctx += buf[k] * cw2[k * H + t];
    // --- LN + z head ---
    float s1 = ctx, s2 = ctx * ctx;
    for (int off = 32; off; off >>= 1) { s1 += __shfl_down(s1, off); s2 += __shfl_down(s2, off); }
    if ((t & 63) == 0) { r1[t >> 6] = s1; r2[t >> 6] = s2; }
    __syncthreads();
    float mean = (r1[0] + r1[1]) * (1.f / H);
    float var  = (r2[0] + r2[1]) * (1.f / H) - mean * mean;
    float xn = (ctx - mean) * rsqrtf(var + EPS_LN) * ln1g[t] + ln1b[t];
    __syncthreads();
    buf[t] = xn;
    __syncthreads();
    float a2 = zb1[t];
    for (int k = 0; k < H; ++k) a2 += buf[k] * zw1[k * H + t];
    float p = gelu_exact(a2) * zw2[t];
    for (int off = 32; off; off >>= 1) p += __shfl_down(p, off);
    if ((t & 63) == 0) r1[t >> 6] = p;
    __syncthreads();
    if (t == 0) out[(size_t)g * 3 + 0] = r1[0] + r1[1] + zb2[0];
}

// ---- K4: edge MLP via MFMA with LN folded into weights ----------------------
// block = 64 edges, 4 waves of 16 edges; A-fragments gathered straight into
// registers (lane(quad,n16) holds A[m=n16][k=s*32+quad*8+j]); LN stats via
// shfl_xor over quads; mu/inv applied in epilogue; sumexp accumulated here.
__global__ __launch_bounds__(256) void k_edges(
    const float* __restrict__ node_tokens, const float* __restrict__ question,
    const float* __restrict__ edge_tokens, const int* __restrict__ edge_batch,
    const int* __restrict__ edge_index,
    const unsigned short* __restrict__ bwbf, const float* __restrict__ colsum,
    const float* __restrict__ bb1p, const float* __restrict__ bw2,
    const float* __restrict__ bb2, float* __restrict__ logits,
    float* __restrict__ sumexp)
{
    __shared__ unsigned short bstage[4096];   // 8 KB
    int t = threadIdx.x, lane = t & 63, w = t >> 6;
    int quad = lane >> 4, n16 = lane & 15;
    int e0 = blockIdx.x * 64;
    int e = e0 + w * 16 + n16;
    int ec = e < NEDGES ? e : NEDGES - 1;
    int qrow = edge_batch[ec];
    int trow = edge_index[NEDGES + ec];
    const float4* ep = (const float4*)(edge_tokens + (size_t)ec * H);
    const float4* qp = (const float4*)(question + (size_t)qrow * H);
    const float4* np_ = (const float4*)(node_tokens + (size_t)trow * H);

    float s1 = 0.f, s2 = 0.f;
    short8 frag[12];
    #pragma unroll
    for (int s = 0; s < 12; ++s) {
        int c0 = s * 8 + quad * 2;          // float4 index 0..95 of the 3H row
        const float4* base = (s < 4) ? ep : (s < 8) ? qp : np_;
        int cc = c0 - ((s < 4) ? 0 : (s < 8) ? 32 : 64);
        float4 v0 = base[cc], v1 = base[cc + 1];
        s1 += v0.x + v0.y + v0.z + v0.w + v1.x + v1.y + v1.z + v1.w;
        s2 += v0.x*v0.x + v0.y*v0.y + v0.z*v0.z + v0.w*v0.w
            + v1.x*v1.x + v1.y*v1.y + v1.z*v1.z + v1.w*v1.w;
        short8 f;
        f[0] = (short)f2bf(v0.x); f[1] = (short)f2bf(v0.y);
        f[2] = (short)f2bf(v0.z); f[3] = (short)f2bf(v0.w);
        f[4] = (short)f2bf(v1.x); f[5] = (short)f2bf(v1.y);
        f[6] = (short)f2bf(v1.z); f[7] = (short)f2bf(v1.w);
        frag[s] = f;
    }
    // full-row stats: reduce across the 4 quads sharing this edge row
    s1 += __shfl_xor(s1, 16); s1 += __shfl_xor(s1, 32);
    s2 += __shfl_xor(s2, 16); s2 += __shfl_xor(s2, 32);
    float mu  = s1 * (1.f / 384.f);
    float inv = rsqrtf(s2 * (1.f / 384.f) - mu * mu + EPS_LN);

    f32x4 acc[8];
    #pragma unroll
    for (int q = 0; q < 8; ++q) acc[q] = (f32x4){0.f, 0.f, 0.f, 0.f};

    #pragma unroll
    for (int s = 0; s < 12; ++s) {
        __syncthreads();
        {   // stage 8 KB B-chunk (L2-hot; same 96 KB read by every block)
            const uint4* src = (const uint4*)(bwbf + s * 4096);
            uint4* dst = (uint4*)bstage;
            dst[t] = src[t];
            dst[t + 256] = src[t + 256];
        }
        __syncthreads();
        #pragma unroll
        for (int t8 = 0; t8 < 8; ++t8) {
            short8 b = *(const short8*)&bstage[(t8 * 64 + lane) * 8];
            acc[t8] = __builtin_amdgcn_mfma_f32_16x16x32_bf16(frag[s], b, acc[t8], 0, 0, 0);
        }
    }

    // epilogue: y = (acc - mu*colsum)*inv + bb1p ; logit = sum gelu(y)*bw2 + bb2
    float csv[8], bbv[8], w2v[8];
    #pragma unroll
    for (int t8 = 0; t8 < 8; ++t8) {
        int n = t8 * 16 + n16;
        csv[t8] = colsum[n]; bbv[t8] = bb1p[n]; w2v[t8] = bw2[n];
    }
    float bb2v = bb2[0];
    #pragma unroll
    for (int r = 0; r < 4; ++r) {
        float mu_r  = __shfl(mu,  quad * 4 + r);
        float inv_r = __shfl(inv, quad * 4 + r);
        float ssum = 0.f;
        #pragma unroll
        for (int t8 = 0; t8 < 8; ++t8) {
            float y = (acc[t8][r] - mu_r * csv[t8]) * inv_r + bbv[t8];
            ssum += gelu_exact(y) * w2v[t8];
        }
        ssum += __shfl_xor(ssum, 1);
        ssum += __shfl_xor(ssum, 2);
        ssum += __shfl_xor(ssum, 4);
        ssum += __shfl_xor(ssum, 8);
        if (n16 == 0) {
            int ei = e0 + w * 16 + quad * 4 + r;
            if (ei < NEDGES) {
                float lg = ssum + bb2v;
                logits[ei] = lg;
                // logits are O(1): exp-sum without max-shift is safe
                atomicAdd(&sumexp[edge_index[NEDGES + ei]], expf(lg));
            }
        }
    }
}

// ---- K6: masked per-graph sum of log-probs (LDS slot aggregation) -----------
__global__ __launch_bounds__(256) void k_logpb(
    const float* __restrict__ logits,
    const int* __restrict__ edge_index,
    const int* __restrict__ edge_batch,
    const void* __restrict__ mask,
    const int* __restrict__ flag,
    const float* __restrict__ sumexp,
    float* __restrict__ logpb, int* __restrict__ selcnt)
{
    __shared__ float lacc[8];
    __shared__ int lcnt[8];
    __shared__ int g0s, big;
    int t = threadIdx.x;
    int e0 = blockIdx.x * 256;
    if (t == 0) {
        int ga = edge_batch[e0 < NEDGES ? e0 : NEDGES - 1];
        int el = e0 + 255; if (el >= NEDGES) el = NEDGES - 1;
        int gb = edge_batch[el];
        g0s = ga; big = (gb - ga > 7);
    }
    if (t < 8) { lacc[t] = 0.f; lcnt[t] = 0; }
    __syncthreads();
    int e = e0 + t;
    if (e < NEDGES) {
        int mode = *flag;
        bool sel;
        if (mode & 2)      sel = ((const float*)mask)[e] != 0.f;
        else if (mode & 1) sel = ((const unsigned char*)mask)[e] != 0;
        else               sel = ((const int*)mask)[e] != 0;
        if (sel) {
            int tg = edge_index[NEDGES + e];
            float lp = logits[e] - logf(sumexp[tg]);
            int g = edge_batch[e];
            if (!big) {
                atomicAdd(&lacc[g - g0s], lp);
                atomicAdd(&lcnt[g - g0s], 1);
            } else {
                atomicAdd(&logpb[g], lp);
                atomicAdd(&selcnt[g], 1);
            }
        }
    }
    __syncthreads();
    if (t < 8 && !big && lcnt[t] > 0) {
        atomicAdd(&logpb[g0s + t], lacc[t]);
        atomicAdd(&selcnt[g0s + t], lcnt[t]);
    }
}

// ---- K7: finalize out[:,1] and out[:,2] -------------------------------------
__global__ __launch_bounds__(1024) void k_final(const float* __restrict__ logpb,
                                                const int* __restrict__ selcnt,
                                                float* __restrict__ out)
{
    int g = threadIdx.x;
    float lpb = logpb[g];
    int has = selcnt[g] > 0;
    float s = has ? -lpb : 0.f;
    int c = has;
    __shared__ float rn[16];
    __shared__ int rh[16];
    __shared__ float pbnll_s;
    for (int off = 32; off; off >>= 1) { s += __shfl_down(s, off); c += __shfl_down(c, off); }
    if ((g & 63) == 0) { rn[g >> 6] = s; rh[g >> 6] = c; }
    __syncthreads();
    if (g == 0) {
        float ts = 0.f; int tc = 0;
        for (int i = 0; i < 16; ++i) { ts += rn[i]; tc += rh[i]; }
        pbnll_s = ts / (float)(tc > 0 ? tc : 1);
    }
    __syncthreads();
    out[(size_t)g * 3 + 1] = lpb;
    out[(size_t)g * 3 + 2] = pbnll_s;
}

extern "C" void kernel_launch(void* const* d_in, const int* in_sizes, int n_in,
                              void* d_out, int out_size, void* d_ws, size_t ws_size,
                              hipStream_t stream) {
    const float* node_tokens = (const float*)d_in[0];
    const float* question    = (const float*)d_in[1];
    const float* edge_tokens = (const float*)d_in[2];
    const int*   locals_     = (const int*)d_in[3];
    const int*   ptr         = (const int*)d_in[4];
    const int*   edge_batch  = (const int*)d_in[5];
    const void*  mask        = d_in[6];
    const int*   edge_index  = (const int*)d_in[7];
    const float* ln1g = (const float*)d_in[8];
    const float* ln1b = (const float*)d_in[9];
    const float* zw1  = (const float*)d_in[10];
    const float* zb1  = (const float*)d_in[11];
    const float* zw2  = (const float*)d_in[12];
    const float* zb2  = (const float*)d_in[13];
    const float* cw1  = (const float*)d_in[14];
    const float* cb1  = (const float*)d_in[15];
    const float* cw2  = (const float*)d_in[16];
    const float* cb2  = (const float*)d_in[17];
    const float* blng = (const float*)d_in[18];
    const float* blnb = (const float*)d_in[19];
    const float* bw1  = (const float*)d_in[20];
    const float* bb1  = (const float*)d_in[21];
    const float* bw2  = (const float*)d_in[22];
    const float* bb2  = (const float*)d_in[23];
    float* out = (float*)d_out;

    // workspace layout (float units)
    float* ws = (float*)d_ws;
    float* sumexp  = ws;                                // 100000 (zeroed)
    float* logpb   = ws + 100000;                       // 1024  (zeroed)
    int*   selcnt  = (int*)(ws + 101024);               // 1024  (zeroed)
    int*   flag    = (int*)(ws + 102048);               // 1     (zeroed)
    float* logits  = ws + 102052;                       // 500000
    float* colsum  = ws + 602052;                       // 128
    float* bb1p    = ws + 602180;                       // 128
    unsigned short* bwbf = (unsigned short*)(ws + 602308); // 49152 bf16 (16B-aligned)

    hipMemsetAsync(d_ws, 0, (size_t)102049 * 4, stream);
    k_probe_mask<<<1, 256, 0, stream>>>((const unsigned*)mask, flag);
    k_prep<<<192, 256, 0, stream>>>(bw1, blng, bwbf);
    k_prep2<<<1, 128, 0, stream>>>(bw1, blng, blnb, bb1, colsum, bb1p);
    k_graph<<<G_NUM, 128, 0, stream>>>(node_tokens, question, locals_, ptr,
                                       cw1, cb1, cw2, cb2, ln1g, ln1b,
                                       zw1, zb1, zw2, zb2, out);
    k_edges<<<(NEDGES + 63) / 64, 256, 0, stream>>>(node_tokens, question, edge_tokens,
                                                    edge_batch, edge_index, bwbf,
                                                    colsum, bb1p, bw2, bb2,
                                                    logits, sumexp);
    int eb = (NEDGES + 255) / 256;
    k_logpb<<<eb, 256, 0, stream>>>(logits, edge_index, edge_batch, mask, flag,
                                    sumexp, logpb, selcnt);
    k_final<<<1, 1024, 0, stream>>>(logpb, selcnt, out);
}